// Round 8
// baseline (695.949 us; speedup 1.0000x reference)
//
#include <hip/hip_runtime.h>
#include <cstdint>
#include <cstddef>

// GAT layer, N=8192, F=128.  Round 11: k2 adj path -> page-local ballot-pack.
// kA  : wh only (256 blocks): Wh = h@W -> Bpack + s12 + per-block max -> M2v
// k1c : reduce 256 block-maxes -> M2; per-index exp factors
// k2  : S=16 j-chunks, 1 wave = 32 rows x 128 f, NO LDS / NO barriers.
//       adj read in 256-col "supers": 32 loads of 1 row x 1KB CONTIGUOUS each
//       (DRAM page-local, R6-pack-proven pattern) -> __ballot x4 -> exec-masked
//       distribute to lane m==r (8 u32 masks/lane).  NO shfl chain.  Mask build
//       for super s+1 pipelined across super s's 8 tiles (2-batch ping-pong).
//       Score gates = const-mask bit tests on pre-shifted ballot words.
// k3  : combine S partials, ELU, store.
// R10 post-mortem: k2 ~140us (R8/R9 A/B) vs 7us MFMA + 24us VALU + 27us BW ->
// latency-bound on (a) 8-rows-x-32KB-stride page scatter per load, (b) 13-deep
// serial shfl/bpermute chain.  This round removes both.

#define NROW 8192
#define FDIM 128

typedef _Float16 f16;
typedef f16 f16x8 __attribute__((ext_vector_type(8)));
typedef float f32x4 __attribute__((ext_vector_type(4)));
typedef float f32x16 __attribute__((ext_vector_type(16)));

// workspace byte offsets
#define WS_BP  (2u*1024u*1024u)              // f16 Bpack[512][4][64][8]  : 2 MiB
#define WS_S12 (4u*1024u*1024u)              // float2 s12[8192]          : 64 KiB
#define WS_RC  (WS_S12 + 64u*1024u)          // float4 RC[8192]           : 128 KiB
#define WS_EF  (WS_RC + 128u*1024u)          // float2 EF[8192]           : 64 KiB
#define WS_M2  (WS_EF + 64u*1024u)           // float M2v[256] (pad 4K)
#define WS_PWS (WS_M2 + 4u*1024u)            // float Pws[S][8192][128]   : S*4 MiB
// Dws = WS_PWS + S*4MiB : float Dws[S][8192]

// ---------------- kA: wh + s12 + block max ----------------
__global__ __launch_bounds__(256) void kA_wh(const float* __restrict__ h,
                                             const float* __restrict__ W,
                                             const float* __restrict__ a,
                                             f16* __restrict__ Bp,
                                             float2* __restrict__ s12,
                                             float* __restrict__ M2v) {
  __shared__ float smem[4736];  // hT[128][36] -> WhS[32][132] + part[2][8][32]
  const int bid = (int)blockIdx.x;
  const int t = (int)threadIdx.x;

  const int rb = bid * 32;
  const f32x4* hv = (const f32x4*)(h + (size_t)rb * FDIM);
#pragma unroll
  for (int i = 0; i < 4; ++i) {
    int fidx = t + i * 256;
    f32x4 v = hv[fidx];
    int e0 = fidx * 4;
    int r = e0 >> 7, k = e0 & 127;
    smem[(k + 0) * 36 + r] = v[0];
    smem[(k + 1) * 36 + r] = v[1];
    smem[(k + 2) * 36 + r] = v[2];
    smem[(k + 3) * 36 + r] = v[3];
  }
  __syncthreads();
  const int f = t & 127, rh = t >> 7;
  f32x4 z = {0.f, 0.f, 0.f, 0.f};
  f32x4 acc0 = z, acc1 = z, acc2 = z, acc3 = z;
  for (int k = 0; k < 128; ++k) {
    float w = W[k * FDIM + f];
    const f32x4* hp = (const f32x4*)(smem + k * 36 + rh * 16);
    acc0 += hp[0] * w;
    acc1 += hp[1] * w;
    acc2 += hp[2] * w;
    acc3 += hp[3] * w;
  }
  union { f16 hx[16]; uint4 u[2]; } pk;
#pragma unroll
  for (int q = 0; q < 4; ++q) {
    pk.hx[0 + q]  = (f16)acc0[q];   // hx[i] = Wh[rb + rh*16 + i][f]
    pk.hx[4 + q]  = (f16)acc1[q];
    pk.hx[8 + q]  = (f16)acc2[q];
    pk.hx[12 + q] = (f16)acc3[q];
  }
  // Bpack[jt=j/16][nt=f/32][lane=(f&31)+32*kb][e] = Wh[jt*16+kb*8+e][f]
  f16* bdst = Bp + ((size_t)((bid * 2 + rh) * 4 + (f >> 5)) * 64 + (f & 31)) * 8;
  *(uint4*)bdst = pk.u[0];
  *(uint4*)(bdst + 256) = pk.u[1];   // +32 lanes * 8

  // s12: transpose fp32 acc into LDS WhS[32][132], then f-reduce
  __syncthreads();  // all hT reads done; reuse smem
#pragma unroll
  for (int q = 0; q < 4; ++q) {
    smem[(rh * 16 + 0  + q) * 132 + f] = acc0[q];
    smem[(rh * 16 + 4  + q) * 132 + f] = acc1[q];
    smem[(rh * 16 + 8  + q) * 132 + f] = acc2[q];
    smem[(rh * 16 + 12 + q) * 132 + f] = acc3[q];
  }
  __syncthreads();
  {
    const int row = t & 31, fc = t >> 5;  // 8 chunks of 16 f
    const float* wrow = smem + row * 132 + fc * 16;
    float s1 = 0.f, s2 = 0.f;
#pragma unroll
    for (int ff = 0; ff < 16; ++ff) {
      float wv = wrow[ff];
      int fg = fc * 16 + ff;
      s1 = fmaf(wv, a[fg], s1);
      s2 = fmaf(wv, a[128 + fg], s2);
    }
    float* part = smem + 4224;  // [2][8][32], disjoint from WhS (0..4223)
    part[0 * 256 + fc * 32 + row] = s1;
    part[1 * 256 + fc * 32 + row] = s2;
    __syncthreads();
    if (t < 32) {
      float s1t = 0.f, s2t = 0.f;
#pragma unroll
      for (int c2 = 0; c2 < 8; ++c2) {
        s1t += part[c2 * 32 + t];
        s2t += part[256 + c2 * 32 + t];
      }
      s12[rb + t] = make_float2(s1t, s2t);
      float mx = s2t;
#pragma unroll
      for (int off = 16; off; off >>= 1) mx = fmaxf(mx, __shfl_xor(mx, off, 64));
      if (t == 0) M2v[bid] = mx;  // plain store, no atomics/init needed
    }
  }
}

// ---------------- k1c: reduce M2; per-index exp factors ----------------
__global__ __launch_bounds__(256) void k1c_prep(const float2* __restrict__ s12,
                                                const float* __restrict__ M2v,
                                                float4* __restrict__ RC,
                                                float2* __restrict__ EF) {
  __shared__ float red[4];
  const int t = (int)threadIdx.x;
  float v = M2v[t];  // 256 block maxes
#pragma unroll
  for (int off = 32; off; off >>= 1) v = fmaxf(v, __shfl_xor(v, off, 64));
  if ((t & 63) == 0) red[t >> 6] = v;
  __syncthreads();
  float M2 = fmaxf(fmaxf(red[0], red[1]), fmaxf(red[2], red[3]));
  int j = (int)blockIdx.x * 256 + t;
  float2 s = s12[j];
  float c = s.x + M2;
  c = fmaxf(c, 0.2f * c);  // upper bound on all row scores => p <= 1
  RC[j] = make_float4(__expf(-s.x), __expf(s.x - c), __expf(0.2f * s.x - c), 0.f);
  EF[j] = make_float2(__expf(s.y), __expf(0.2f * s.y));
}

// ---------------- k2: fused adj-stream + masked-softmax @ Wh ----------------
// Masks: ballot_e of row r (u64): bit L = adj[rb+r][scol + 4L + e] > 0.
// Lane m keeps row m's 8 words (lo/hi of e=0..3).  Tile tt (32 cols within the
// 256-col super): gate(af0[q]) = ballot_{q&3} bit (8tt + 2kb + (q>>2));
// gate(af1[q]) = same + 4.  Verified against Bpack's j = jt*16 + kb*8 + e map.
__global__ __launch_bounds__(256, 2) void k2_main(const int* __restrict__ adj,
                                                  const f16* __restrict__ Bp,
                                                  const float4* __restrict__ RC,
                                                  const float* __restrict__ EF,
                                                  float* __restrict__ Pws,
                                                  float* __restrict__ Dws,
                                                  int jspan) {
  const int tid = (int)threadIdx.x;
  const int L = tid & 63, w = tid >> 6;
  const int wid = (int)blockIdx.x * 4 + w;
  const int rg = wid & 255;
  const int c = wid >> 8;
  const int rb = rg * 32;
  const int m = L & 31, kb = L >> 5;
  const int row = rb + m;
  const int j0 = c * jspan;
  const int nsup = jspan >> 8;  // 256-col supers; 2 at S=16 (even for S in {2,8,16})

  const float4 rc = RC[row];
  const float tau = rc.x, kap1 = rc.y, kap2 = rc.z;
  const unsigned kb2 = (unsigned)(kb * 2);

  // row rb, this lane's 16B col slot (cols 4L..4L+3 of a 256-col super)
  const int* abase = adj + (size_t)rb * NROW + j0 + 4 * L;
  const f32x4* ep = (const f32x4*)(EF + 2 * (j0 + kb * 8));
  const f16* bp = Bp + (size_t)(j0 >> 4) * 2048 + L * 8;  // tile stride 2048 f16

  f32x4 E0 = ep[0], E1 = ep[1], E2 = ep[2], E3 = ep[3];
  f32x4 E4 = ep[8], E5 = ep[9], E6 = ep[10], E7 = ep[11];

  f32x16 zz = {0.f};
  f32x16 acc[4] = {zz, zz, zz, zz};
  float dloc = 0.f;

  // mask scalars (this lane's row): current super (Wl/Wh), next super (Nl/Nh)
  unsigned Wl0 = 0, Wl1 = 0, Wl2 = 0, Wl3 = 0, Wh0 = 0, Wh1 = 0, Wh2 = 0, Wh3 = 0;
  unsigned Nl0 = 0, Nl1 = 0, Nl2 = 0, Nl3 = 0, Nh0 = 0, Nh1 = 0, Nh2 = 0, Nh3 = 0;
  int4 Ra0, Ra1, Ra2, Ra3;  // row-load batch A (rows 4k..4k+3)
  int4 Rb0, Rb1, Rb2, Rb3;  // row-load batch B
  int itile = 0;            // global tile index (B addressing)

// issue 4 contiguous 1-row loads (rows 4k..4k+3) at col offset scol
#define ISSUE4(QA, QB, QC, QD, k, scol) do {                         \
    const int* ap_ = abase + (size_t)(4 * (k)) * NROW + (scol);      \
    QA = *(const int4*)(ap_);                                        \
    QB = *(const int4*)(ap_ + NROW);                                 \
    QC = *(const int4*)(ap_ + 2 * NROW);                             \
    QD = *(const int4*)(ap_ + 3 * NROW);                             \
  } while (0)

#define PACKROW(Q, r, DL0, DL1, DL2, DL3, DH0, DH1, DH2, DH3) do {   \
    unsigned long long b0_ = __ballot((Q).x > 0);                    \
    unsigned long long b1_ = __ballot((Q).y > 0);                    \
    unsigned long long b2_ = __ballot((Q).z > 0);                    \
    unsigned long long b3_ = __ballot((Q).w > 0);                    \
    if (m == (r)) {                                                  \
      DL0 = (unsigned)b0_; DH0 = (unsigned)(b0_ >> 32);              \
      DL1 = (unsigned)b1_; DH1 = (unsigned)(b1_ >> 32);              \
      DL2 = (unsigned)b2_; DH2 = (unsigned)(b2_ >> 32);              \
      DL3 = (unsigned)b3_; DH3 = (unsigned)(b3_ >> 32);              \
    }                                                                \
  } while (0)

#define PACK4(QA, QB, QC, QD, k, DL0, DL1, DL2, DL3, DH0, DH1, DH2, DH3) do { \
    PACKROW(QA, 4 * (k) + 0, DL0, DL1, DL2, DL3, DH0, DH1, DH2, DH3);         \
    PACKROW(QB, 4 * (k) + 1, DL0, DL1, DL2, DL3, DH0, DH1, DH2, DH3);         \
    PACKROW(QC, 4 * (k) + 2, DL0, DL1, DL2, DL3, DH0, DH1, DH2, DH3);         \
    PACKROW(QD, 4 * (k) + 3, DL0, DL1, DL2, DL3, DH0, DH1, DH2, DH3);         \
  } while (0)

// one 32-col tile: B loads, gate+score from masks, EF advance, 8 MFMA
#define TILE(tt, SL0, SL1, SL2, SL3, SH0, SH1, SH2, SH3) do {        \
    const f16* bt = bp + (size_t)itile * 4096;                       \
    f16x8 B00 = *(const f16x8*)(bt);                                 \
    f16x8 B01 = *(const f16x8*)(bt + 512);                           \
    f16x8 B02 = *(const f16x8*)(bt + 1024);                          \
    f16x8 B03 = *(const f16x8*)(bt + 1536);                          \
    f16x8 B10 = *(const f16x8*)(bt + 2048);                          \
    f16x8 B11 = *(const f16x8*)(bt + 2560);                          \
    f16x8 B12 = *(const f16x8*)(bt + 3072);                          \
    f16x8 B13 = *(const f16x8*)(bt + 3584);                          \
    unsigned sh_ = kb2 + 8u * ((tt) & 3);                            \
    unsigned vb0 = (((tt) < 4) ? SL0 : SH0) >> sh_;                  \
    unsigned vb1 = (((tt) < 4) ? SL1 : SH1) >> sh_;                  \
    unsigned vb2 = (((tt) < 4) ? SL2 : SH2) >> sh_;                  \
    unsigned vb3 = (((tt) < 4) ? SL3 : SH3) >> sh_;                  \
    unsigned vc0 = vb0 >> 4, vc1 = vb1 >> 4, vc2 = vb2 >> 4, vc3 = vb3 >> 4; \
    f16x8 af0, af1;                                                  \
    { float p;                                                       \
      p = (E0[0] > tau) ? E0[0] * kap1 : E0[1] * kap2; p = (vb0 & 1u) ? p : 0.f; dloc += p; af0[0] = (f16)p; \
      p = (E0[2] > tau) ? E0[2] * kap1 : E0[3] * kap2; p = (vb1 & 1u) ? p : 0.f; dloc += p; af0[1] = (f16)p; \
      p = (E1[0] > tau) ? E1[0] * kap1 : E1[1] * kap2; p = (vb2 & 1u) ? p : 0.f; dloc += p; af0[2] = (f16)p; \
      p = (E1[2] > tau) ? E1[2] * kap1 : E1[3] * kap2; p = (vb3 & 1u) ? p : 0.f; dloc += p; af0[3] = (f16)p; \
      p = (E2[0] > tau) ? E2[0] * kap1 : E2[1] * kap2; p = (vb0 & 2u) ? p : 0.f; dloc += p; af0[4] = (f16)p; \
      p = (E2[2] > tau) ? E2[2] * kap1 : E2[3] * kap2; p = (vb1 & 2u) ? p : 0.f; dloc += p; af0[5] = (f16)p; \
      p = (E3[0] > tau) ? E3[0] * kap1 : E3[1] * kap2; p = (vb2 & 2u) ? p : 0.f; dloc += p; af0[6] = (f16)p; \
      p = (E3[2] > tau) ? E3[2] * kap1 : E3[3] * kap2; p = (vb3 & 2u) ? p : 0.f; dloc += p; af0[7] = (f16)p; \
      p = (E4[0] > tau) ? E4[0] * kap1 : E4[1] * kap2; p = (vc0 & 1u) ? p : 0.f; dloc += p; af1[0] = (f16)p; \
      p = (E4[2] > tau) ? E4[2] * kap1 : E4[3] * kap2; p = (vc1 & 1u) ? p : 0.f; dloc += p; af1[1] = (f16)p; \
      p = (E5[0] > tau) ? E5[0] * kap1 : E5[1] * kap2; p = (vc2 & 1u) ? p : 0.f; dloc += p; af1[2] = (f16)p; \
      p = (E5[2] > tau) ? E5[2] * kap1 : E5[3] * kap2; p = (vc3 & 1u) ? p : 0.f; dloc += p; af1[3] = (f16)p; \
      p = (E6[0] > tau) ? E6[0] * kap1 : E6[1] * kap2; p = (vc0 & 2u) ? p : 0.f; dloc += p; af1[4] = (f16)p; \
      p = (E6[2] > tau) ? E6[2] * kap1 : E6[3] * kap2; p = (vc1 & 2u) ? p : 0.f; dloc += p; af1[5] = (f16)p; \
      p = (E7[0] > tau) ? E7[0] * kap1 : E7[1] * kap2; p = (vc2 & 2u) ? p : 0.f; dloc += p; af1[6] = (f16)p; \
      p = (E7[2] > tau) ? E7[2] * kap1 : E7[3] * kap2; p = (vc3 & 2u) ? p : 0.f; dloc += p; af1[7] = (f16)p; \
    }                                                                \
    ep += 16;  /* 64B past EF end on the final tile lands in M2 pad: safe */ \
    E0 = ep[0]; E1 = ep[1]; E2 = ep[2]; E3 = ep[3];                  \
    E4 = ep[8]; E5 = ep[9]; E6 = ep[10]; E7 = ep[11];                \
    __builtin_amdgcn_s_setprio(1);                                   \
    acc[0] = __builtin_amdgcn_mfma_f32_32x32x16_f16(af0, B00, acc[0], 0, 0, 0); \
    acc[1] = __builtin_amdgcn_mfma_f32_32x32x16_f16(af0, B01, acc[1], 0, 0, 0); \
    acc[2] = __builtin_amdgcn_mfma_f32_32x32x16_f16(af0, B02, acc[2], 0, 0, 0); \
    acc[3] = __builtin_amdgcn_mfma_f32_32x32x16_f16(af0, B03, acc[3], 0, 0, 0); \
    acc[0] = __builtin_amdgcn_mfma_f32_32x32x16_f16(af1, B10, acc[0], 0, 0, 0); \
    acc[1] = __builtin_amdgcn_mfma_f32_32x32x16_f16(af1, B11, acc[1], 0, 0, 0); \
    acc[2] = __builtin_amdgcn_mfma_f32_32x32x16_f16(af1, B12, acc[2], 0, 0, 0); \
    acc[3] = __builtin_amdgcn_mfma_f32_32x32x16_f16(af1, B13, acc[3], 0, 0, 0); \
    __builtin_amdgcn_s_setprio(0);                                   \
    ++itile;                                                         \
  } while (0)

// one 256-col super: consume S-masks, build N-masks for col offset scoln
#define SUPER(SL0, SL1, SL2, SL3, SH0, SH1, SH2, SH3,                \
              NL0, NL1, NL2, NL3, NH0, NH1, NH2, NH3, hasn, scoln) do {       \
    TILE(0, SL0, SL1, SL2, SL3, SH0, SH1, SH2, SH3);                          \
    if (hasn) ISSUE4(Ra0, Ra1, Ra2, Ra3, 0, scoln);                           \
    TILE(1, SL0, SL1, SL2, SL3, SH0, SH1, SH2, SH3);                          \
    if (hasn) ISSUE4(Rb0, Rb1, Rb2, Rb3, 1, scoln);                           \
    if (hasn) PACK4(Ra0, Ra1, Ra2, Ra3, 0, NL0, NL1, NL2, NL3, NH0, NH1, NH2, NH3); \
    TILE(2, SL0, SL1, SL2, SL3, SH0, SH1, SH2, SH3);                          \
    if (hasn) ISSUE4(Ra0, Ra1, Ra2, Ra3, 2, scoln);                           \
    if (hasn) PACK4(Rb0, Rb1, Rb2, Rb3, 1, NL0, NL1, NL2, NL3, NH0, NH1, NH2, NH3); \
    TILE(3, SL0, SL1, SL2, SL3, SH0, SH1, SH2, SH3);                          \
    if (hasn) ISSUE4(Rb0, Rb1, Rb2, Rb3, 3, scoln);                           \
    if (hasn) PACK4(Ra0, Ra1, Ra2, Ra3, 2, NL0, NL1, NL2, NL3, NH0, NH1, NH2, NH3); \
    TILE(4, SL0, SL1, SL2, SL3, SH0, SH1, SH2, SH3);                          \
    if (hasn) ISSUE4(Ra0, Ra1, Ra2, Ra3, 4, scoln);                           \
    if (hasn) PACK4(Rb0, Rb1, Rb2, Rb3, 3, NL0, NL1, NL2, NL3, NH0, NH1, NH2, NH3); \
    TILE(5, SL0, SL1, SL2, SL3, SH0, SH1, SH2, SH3);                          \
    if (hasn) ISSUE4(Rb0, Rb1, Rb2, Rb3, 5, scoln);                           \
    if (hasn) PACK4(Ra0, Ra1, Ra2, Ra3, 4, NL0, NL1, NL2, NL3, NH0, NH1, NH2, NH3); \
    TILE(6, SL0, SL1, SL2, SL3, SH0, SH1, SH2, SH3);                          \
    if (hasn) ISSUE4(Ra0, Ra1, Ra2, Ra3, 6, scoln);                           \
    if (hasn) PACK4(Rb0, Rb1, Rb2, Rb3, 5, NL0, NL1, NL2, NL3, NH0, NH1, NH2, NH3); \
    TILE(7, SL0, SL1, SL2, SL3, SH0, SH1, SH2, SH3);                          \
    if (hasn) ISSUE4(Rb0, Rb1, Rb2, Rb3, 7, scoln);                           \
    if (hasn) PACK4(Ra0, Ra1, Ra2, Ra3, 6, NL0, NL1, NL2, NL3, NH0, NH1, NH2, NH3); \
    if (hasn) PACK4(Rb0, Rb1, Rb2, Rb3, 7, NL0, NL1, NL2, NL3, NH0, NH1, NH2, NH3); \
  } while (0)

  // prologue: build masks for super 0 (2-batch pipelined)
  ISSUE4(Ra0, Ra1, Ra2, Ra3, 0, 0);
  ISSUE4(Rb0, Rb1, Rb2, Rb3, 1, 0);
  PACK4(Ra0, Ra1, Ra2, Ra3, 0, Wl0, Wl1, Wl2, Wl3, Wh0, Wh1, Wh2, Wh3);
  ISSUE4(Ra0, Ra1, Ra2, Ra3, 2, 0);
  PACK4(Rb0, Rb1, Rb2, Rb3, 1, Wl0, Wl1, Wl2, Wl3, Wh0, Wh1, Wh2, Wh3);
  ISSUE4(Rb0, Rb1, Rb2, Rb3, 3, 0);
  PACK4(Ra0, Ra1, Ra2, Ra3, 2, Wl0, Wl1, Wl2, Wl3, Wh0, Wh1, Wh2, Wh3);
  ISSUE4(Ra0, Ra1, Ra2, Ra3, 4, 0);
  PACK4(Rb0, Rb1, Rb2, Rb3, 3, Wl0, Wl1, Wl2, Wl3, Wh0, Wh1, Wh2, Wh3);
  ISSUE4(Rb0, Rb1, Rb2, Rb3, 5, 0);
  PACK4(Ra0, Ra1, Ra2, Ra3, 4, Wl0, Wl1, Wl2, Wl3, Wh0, Wh1, Wh2, Wh3);
  ISSUE4(Ra0, Ra1, Ra2, Ra3, 6, 0);
  PACK4(Rb0, Rb1, Rb2, Rb3, 5, Wl0, Wl1, Wl2, Wl3, Wh0, Wh1, Wh2, Wh3);
  ISSUE4(Rb0, Rb1, Rb2, Rb3, 7, 0);
  PACK4(Ra0, Ra1, Ra2, Ra3, 6, Wl0, Wl1, Wl2, Wl3, Wh0, Wh1, Wh2, Wh3);
  PACK4(Rb0, Rb1, Rb2, Rb3, 7, Wl0, Wl1, Wl2, Wl3, Wh0, Wh1, Wh2, Wh3);

  for (int ss = 0; ss < nsup; ss += 2) {
    {
      int scoln = (ss + 1) * 256;  // ss+1 < nsup always (ss <= nsup-2)
      SUPER(Wl0, Wl1, Wl2, Wl3, Wh0, Wh1, Wh2, Wh3,
            Nl0, Nl1, Nl2, Nl3, Nh0, Nh1, Nh2, Nh3, true, scoln);
    }
    {
      const bool hasn = (ss + 2) < nsup;
      int scoln = hasn ? (ss + 2) * 256 : 0;
      SUPER(Nl0, Nl1, Nl2, Nl3, Nh0, Nh1, Nh2, Nh3,
            Wl0, Wl1, Wl2, Wl3, Wh0, Wh1, Wh2, Wh3, hasn, scoln);
    }
  }

  // partial denominator: combine kb halves; lanes 0..31 hold rows 0..31
  dloc += __shfl_xor(dloc, 32, 64);
  if (L < 32) Dws[(size_t)c * NROW + row] = dloc;

  // partial numerator: C/D layout col=L&31, row=(reg&3)+8*(reg>>2)+4*kb
  float* P = Pws + ((size_t)c * NROW + rb) * FDIM + (L & 31);
#pragma unroll
  for (int nt = 0; nt < 4; ++nt) {
#pragma unroll
    for (int reg = 0; reg < 16; ++reg) {
      int rr = (reg & 3) + 8 * (reg >> 2) + 4 * kb;
      P[(size_t)rr * FDIM + nt * 32] = acc[nt][reg];
    }
  }
}

// ---------------- k3: combine S partials, ELU ----------------
__global__ __launch_bounds__(256) void k3_comb(const float* __restrict__ Pws,
                                               const float* __restrict__ Dws,
                                               float* __restrict__ out, int S) {
  int g = (int)blockIdx.x * 256 + (int)threadIdx.x;  // 0..262143
  int r = g >> 5, f4 = g & 31;
  f32x4 s = {0.f, 0.f, 0.f, 0.f};
  float den = 0.f;
  for (int c2 = 0; c2 < S; ++c2) {
    s += *(const f32x4*)(Pws + ((size_t)c2 * NROW + r) * FDIM + f4 * 4);
    den += Dws[(size_t)c2 * NROW + r];
  }
  float inv = 1.0f / den;
  f32x4 o;
#pragma unroll
  for (int e = 0; e < 4; ++e) {
    float x = s[e] * inv;
    o[e] = x > 0.f ? x : expm1f(x);
  }
  *(f32x4*)(out + (size_t)r * FDIM + f4 * 4) = o;
}

extern "C" void kernel_launch(void* const* d_in, const int* in_sizes, int n_in,
                              void* d_out, int out_size, void* d_ws, size_t ws_size,
                              hipStream_t stream) {
  const float* h = (const float*)d_in[0];
  const int* adj = (const int*)d_in[1];
  const float* W = (const float*)d_in[2];
  const float* a = (const float*)d_in[3];
  float* out = (float*)d_out;
  char* ws = (char*)d_ws;
  f16* Bp = (f16*)(ws + WS_BP);
  float2* s12 = (float2*)(ws + WS_S12);
  float4* RC = (float4*)(ws + WS_RC);
  float2* EF = (float2*)(ws + WS_EF);
  float* M2v = (float*)(ws + WS_M2);

  // S chunks of j; prefer 16 (4096 waves in k2), fall back 8 -> 2
  const size_t partial_bytes = (size_t)NROW * FDIM * 4;  // 4 MiB per chunk
  int S = 2;
  if (ws_size >= WS_PWS + 16 * partial_bytes + 16 * (size_t)NROW * 4) S = 16;
  else if (ws_size >= WS_PWS + 8 * partial_bytes + 8 * (size_t)NROW * 4) S = 8;
  float* Pws = (float*)(ws + WS_PWS);
  float* Dws = (float*)(ws + WS_PWS + (size_t)S * partial_bytes);
  int jspan = NROW / S;

  kA_wh<<<dim3(256), dim3(256), 0, stream>>>(h, W, a, Bp, s12, M2v);
  k1c_prep<<<dim3(32), dim3(256), 0, stream>>>(s12, M2v, RC, EF);
  k2_main<<<dim3(64 * S), dim3(256), 0, stream>>>(adj, Bp, RC, (const float*)EF, Pws, Dws, jspan);
  k3_comb<<<dim3(1024), dim3(256), 0, stream>>>(Pws, Dws, out, S);
}

// Round 9
// 436.151 us; speedup vs baseline: 1.5957x; 1.5957x over previous
//
#include <hip/hip_runtime.h>
#include <cstdint>
#include <cstddef>

// GAT layer, N=8192, F=128.  Round 12: R6 bitmap-k2 x R10 S=16 grid (combine
// the two proven-best pieces; revert R11's spilled ballot rewrite).
// kA  : fused: bids 0..255 wh (Wh->Bpack + s12 + block max); bids 256..2303
//       pack adj>0 -> bitmap bm[rg][jw][m] (8 MiB), int4 + 3x shfl_xor OR.
// k1c : reduce 256 block-maxes -> M2; per-index exp factors
// k2  : bitmap-based masked-softmax @ Wh.  S=16 j-chunks -> 1024 blocks =
//       4 waves/SIMD (VGPR ~116 natural limit).  1 bm dword/lane/iter 2-deep
//       prefetched, EF 1-deep, B 1KB L2 loads, setprio around 8 MFMA.
// k3  : combine S partials, ELU, store.
// Model (fits R5..R11): dur = 275us harness offset + our chain.
// R6 chain: kA 47 + k1c 2 + k2bm(S=8, 2w/SIMD) ~100 + k3 7 = 156 -> 431.
// R10 proved 2->4 w/SIMD helps k2 even with worse mask path.  Here: k2bm at
// 4 w/SIMD pred ~55-75, k3(S=16) ~11 -> chain ~123 -> dur ~398-410.

#define NROW 8192
#define FDIM 128

typedef _Float16 f16;
typedef f16 f16x8 __attribute__((ext_vector_type(8)));
typedef float f32x4 __attribute__((ext_vector_type(4)));
typedef float f32x16 __attribute__((ext_vector_type(16)));

// workspace byte offsets
#define WS_BP  (2u*1024u*1024u)              // f16 Bpack[512][4][64][8]  : 2 MiB
#define WS_S12 (4u*1024u*1024u)              // float2 s12[8192]          : 64 KiB
#define WS_RC  (WS_S12 + 64u*1024u)          // float4 RC[8192]           : 128 KiB
#define WS_EF  (WS_RC + 128u*1024u)          // float2 EF[8192]           : 64 KiB
#define WS_M2  (WS_EF + 64u*1024u)           // float M2v[256] (pad 4K)
#define WS_PWS (WS_M2 + 4u*1024u)            // float Pws[S][8192][128]   : S*4 MiB
// Dws = WS_PWS + S*4MiB : float Dws[S][8192]
// bm  = after Dws       : unsigned bm[256][256][32] : 8 MiB

// ---------------- kA: fused pack || (wh + s12) ----------------
__global__ __launch_bounds__(256) void kA_wh_pack(const float* __restrict__ h,
                                                  const float* __restrict__ W,
                                                  const float* __restrict__ a,
                                                  const int* __restrict__ adj,
                                                  f16* __restrict__ Bp,
                                                  unsigned* __restrict__ bm,
                                                  float2* __restrict__ s12,
                                                  float* __restrict__ M2v) {
  __shared__ float smem[4736];  // hT[128][36] -> WhS[32][132] + part[2][8][32]
  const int bid = (int)blockIdx.x;
  const int t = (int)threadIdx.x;

  if (bid >= 256) {
    // ---- pack part: bm[rg][jw][m] bit b = adj[rg*32+m][jw*32+b] ----
    const int pb = bid - 256;
    const int w = t >> 6, l = t & 63;
    const int r = pb * 4 + w;  // one row per wave
    const int rg = r >> 5, m = r & 31;
    const int* ap = adj + (size_t)r * NROW;
    unsigned* bp = bm + (size_t)rg * (256 * 32) + m;  // + jw*32
    const int g = l >> 3;  // 8-lane group -> one 32-col word
    for (int jb = 0; jb < NROW; jb += 256) {
      int4 v = *(const int4*)(ap + jb + 4 * l);  // lane covers cols 4l..4l+3
      unsigned nib = (v.x > 0 ? 1u : 0u) | (v.y > 0 ? 2u : 0u) |
                     (v.z > 0 ? 4u : 0u) | (v.w > 0 ? 8u : 0u);
      unsigned word = nib << (4 * (l & 7));
      word |= (unsigned)__shfl_xor((int)word, 1, 64);
      word |= (unsigned)__shfl_xor((int)word, 2, 64);
      word |= (unsigned)__shfl_xor((int)word, 4, 64);
      if ((l & 7) == 0) bp[(size_t)((jb >> 5) + g) * 32] = word;
    }
    return;
  }

  // ---- wh part: Wh = h @ W -> Bpack + s12 + block max(s2) ----
  const int rb = bid * 32;
  const f32x4* hv = (const f32x4*)(h + (size_t)rb * FDIM);
#pragma unroll
  for (int i = 0; i < 4; ++i) {
    int fidx = t + i * 256;
    f32x4 v = hv[fidx];
    int e0 = fidx * 4;
    int r = e0 >> 7, k = e0 & 127;
    smem[(k + 0) * 36 + r] = v[0];
    smem[(k + 1) * 36 + r] = v[1];
    smem[(k + 2) * 36 + r] = v[2];
    smem[(k + 3) * 36 + r] = v[3];
  }
  __syncthreads();
  const int f = t & 127, rh = t >> 7;
  f32x4 z = {0.f, 0.f, 0.f, 0.f};
  f32x4 acc0 = z, acc1 = z, acc2 = z, acc3 = z;
  for (int k = 0; k < 128; ++k) {
    float w = W[k * FDIM + f];
    const f32x4* hp = (const f32x4*)(smem + k * 36 + rh * 16);
    acc0 += hp[0] * w;
    acc1 += hp[1] * w;
    acc2 += hp[2] * w;
    acc3 += hp[3] * w;
  }
  union { f16 hx[16]; uint4 u[2]; } pk;
#pragma unroll
  for (int q = 0; q < 4; ++q) {
    pk.hx[0 + q]  = (f16)acc0[q];   // hx[i] = Wh[rb + rh*16 + i][f]
    pk.hx[4 + q]  = (f16)acc1[q];
    pk.hx[8 + q]  = (f16)acc2[q];
    pk.hx[12 + q] = (f16)acc3[q];
  }
  // Bpack[jt=j/16][nt=f/32][lane=(f&31)+32*kb][e] = Wh[jt*16+kb*8+e][f]
  f16* bdst = Bp + ((size_t)((bid * 2 + rh) * 4 + (f >> 5)) * 64 + (f & 31)) * 8;
  *(uint4*)bdst = pk.u[0];
  *(uint4*)(bdst + 256) = pk.u[1];   // +32 lanes * 8

  // s12: transpose fp32 acc into LDS WhS[32][132], then f-reduce
  __syncthreads();  // all hT reads done; reuse smem
#pragma unroll
  for (int q = 0; q < 4; ++q) {
    smem[(rh * 16 + 0  + q) * 132 + f] = acc0[q];
    smem[(rh * 16 + 4  + q) * 132 + f] = acc1[q];
    smem[(rh * 16 + 8  + q) * 132 + f] = acc2[q];
    smem[(rh * 16 + 12 + q) * 132 + f] = acc3[q];
  }
  __syncthreads();
  {
    const int row = t & 31, fc = t >> 5;  // 8 chunks of 16 f
    const float* wrow = smem + row * 132 + fc * 16;
    float s1 = 0.f, s2 = 0.f;
#pragma unroll
    for (int ff = 0; ff < 16; ++ff) {
      float wv = wrow[ff];
      int fg = fc * 16 + ff;
      s1 = fmaf(wv, a[fg], s1);
      s2 = fmaf(wv, a[128 + fg], s2);
    }
    float* part = smem + 4224;  // [2][8][32], disjoint from WhS (0..4223)
    part[0 * 256 + fc * 32 + row] = s1;
    part[1 * 256 + fc * 32 + row] = s2;
    __syncthreads();
    if (t < 32) {
      float s1t = 0.f, s2t = 0.f;
#pragma unroll
      for (int c2 = 0; c2 < 8; ++c2) {
        s1t += part[c2 * 32 + t];
        s2t += part[256 + c2 * 32 + t];
      }
      s12[rb + t] = make_float2(s1t, s2t);
      float mx = s2t;
#pragma unroll
      for (int off = 16; off; off >>= 1) mx = fmaxf(mx, __shfl_xor(mx, off, 64));
      if (t == 0) M2v[bid] = mx;  // plain store, no atomics/init needed
    }
  }
}

// ---------------- k1c: reduce M2; per-index exp factors ----------------
__global__ __launch_bounds__(256) void k1c_prep(const float2* __restrict__ s12,
                                                const float* __restrict__ M2v,
                                                float4* __restrict__ RC,
                                                float2* __restrict__ EF) {
  __shared__ float red[4];
  const int t = (int)threadIdx.x;
  float v = M2v[t];  // 256 block maxes
#pragma unroll
  for (int off = 32; off; off >>= 1) v = fmaxf(v, __shfl_xor(v, off, 64));
  if ((t & 63) == 0) red[t >> 6] = v;
  __syncthreads();
  float M2 = fmaxf(fmaxf(red[0], red[1]), fmaxf(red[2], red[3]));
  int j = (int)blockIdx.x * 256 + t;
  float2 s = s12[j];
  float c = s.x + M2;
  c = fmaxf(c, 0.2f * c);  // upper bound on all row scores => p <= 1
  RC[j] = make_float4(__expf(-s.x), __expf(s.x - c), __expf(0.2f * s.x - c), 0.f);
  EF[j] = make_float2(__expf(s.y), __expf(0.2f * s.y));
}

// ---------------- k2: bitmap masked-softmax @ Wh (R6 structure, S=16) -------
// wave wid: rg = wid&255 (32-row group), c = wid>>8 (j chunk of jspan).
// lane: m = L&31 (row), kb = L>>5 (k-half). Per 32-j iter: 2 A-frags, 8 MFMA.
// bitmap word: one dword/lane/iter, 128 B/wave, 2-deep prefetch.
__global__ __launch_bounds__(256, 2) void k2_main(const unsigned* __restrict__ bm,
                                                  const f16* __restrict__ Bp,
                                                  const float4* __restrict__ RC,
                                                  const float* __restrict__ EF,
                                                  float* __restrict__ Pws,
                                                  float* __restrict__ Dws,
                                                  int jspan) {
  const int tid = (int)threadIdx.x;
  const int L = tid & 63, w = tid >> 6;
  const int wid = (int)blockIdx.x * 4 + w;
  const int rg = wid & 255;
  const int c = wid >> 8;
  const int rb = rg * 32;
  const int m = L & 31, kb = L >> 5;
  const int row = rb + m;
  const int j0 = c * jspan;
  const int niter = jspan >> 5;  // 16 at S=16

  const float4 rc = RC[row];
  const float tau = rc.x, kap1 = rc.y, kap2 = rc.z;

  const unsigned* wbase = bm + ((size_t)rg * 256 + (size_t)(j0 >> 5)) * 32 + m;
  const f32x4* ep = (const f32x4*)(EF + 2 * (j0 + kb * 8));
  const f16* bp = Bp + (size_t)(j0 >> 4) * 2048 + L * 8;  // tile stride 2048 f16

  // prefetch: bitmap 2-deep, EF 1-deep (L2-hot)
  unsigned WD  = wbase[0];
  unsigned WDn = wbase[32];
  f32x4 E0 = ep[0], E1 = ep[1], E2 = ep[2], E3 = ep[3];
  f32x4 E4 = ep[8], E5 = ep[9], E6 = ep[10], E7 = ep[11];

  f32x16 zz = {0.f};
  f32x16 acc[4] = {zz, zz, zz, zz};
  float dloc = 0.f;

  for (int it = 0; it < niter; ++it) {
    // B loads first (L2 ~200cyc hides under the score build below)
    const f16* bt = bp + (size_t)it * 4096;
    f16x8 B00 = *(const f16x8*)(bt);
    f16x8 B01 = *(const f16x8*)(bt + 512);
    f16x8 B02 = *(const f16x8*)(bt + 1024);
    f16x8 B03 = *(const f16x8*)(bt + 1536);
    f16x8 B10 = *(const f16x8*)(bt + 2048);
    f16x8 B11 = *(const f16x8*)(bt + 2560);
    f16x8 B12 = *(const f16x8*)(bt + 3072);
    f16x8 B13 = *(const f16x8*)(bt + 3584);

    // score build: p = adjbit ? exp(leaky(s1+s2)-c) : 0, branch-factored, no exp
    // af0[e] <- bit kb*8+e ; af1[e] <- bit 16+kb*8+e of WD
    const unsigned u0 = WD >> (kb * 8);
    const unsigned u1 = u0 >> 16;
    f16x8 af0, af1;
    {
      float p;
      p = (E0[0] > tau) ? E0[0] * kap1 : E0[1] * kap2; p = (u0 & 1u)   ? p : 0.f; dloc += p; af0[0] = (f16)p;
      p = (E0[2] > tau) ? E0[2] * kap1 : E0[3] * kap2; p = (u0 & 2u)   ? p : 0.f; dloc += p; af0[1] = (f16)p;
      p = (E1[0] > tau) ? E1[0] * kap1 : E1[1] * kap2; p = (u0 & 4u)   ? p : 0.f; dloc += p; af0[2] = (f16)p;
      p = (E1[2] > tau) ? E1[2] * kap1 : E1[3] * kap2; p = (u0 & 8u)   ? p : 0.f; dloc += p; af0[3] = (f16)p;
      p = (E2[0] > tau) ? E2[0] * kap1 : E2[1] * kap2; p = (u0 & 16u)  ? p : 0.f; dloc += p; af0[4] = (f16)p;
      p = (E2[2] > tau) ? E2[2] * kap1 : E2[3] * kap2; p = (u0 & 32u)  ? p : 0.f; dloc += p; af0[5] = (f16)p;
      p = (E3[0] > tau) ? E3[0] * kap1 : E3[1] * kap2; p = (u0 & 64u)  ? p : 0.f; dloc += p; af0[6] = (f16)p;
      p = (E3[2] > tau) ? E3[2] * kap1 : E3[3] * kap2; p = (u0 & 128u) ? p : 0.f; dloc += p; af0[7] = (f16)p;
      p = (E4[0] > tau) ? E4[0] * kap1 : E4[1] * kap2; p = (u1 & 1u)   ? p : 0.f; dloc += p; af1[0] = (f16)p;
      p = (E4[2] > tau) ? E4[2] * kap1 : E4[3] * kap2; p = (u1 & 2u)   ? p : 0.f; dloc += p; af1[1] = (f16)p;
      p = (E5[0] > tau) ? E5[0] * kap1 : E5[1] * kap2; p = (u1 & 4u)   ? p : 0.f; dloc += p; af1[2] = (f16)p;
      p = (E5[2] > tau) ? E5[2] * kap1 : E5[3] * kap2; p = (u1 & 8u)   ? p : 0.f; dloc += p; af1[3] = (f16)p;
      p = (E6[0] > tau) ? E6[0] * kap1 : E6[1] * kap2; p = (u1 & 16u)  ? p : 0.f; dloc += p; af1[4] = (f16)p;
      p = (E6[2] > tau) ? E6[2] * kap1 : E6[3] * kap2; p = (u1 & 32u)  ? p : 0.f; dloc += p; af1[5] = (f16)p;
      p = (E7[0] > tau) ? E7[0] * kap1 : E7[1] * kap2; p = (u1 & 64u)  ? p : 0.f; dloc += p; af1[6] = (f16)p;
      p = (E7[2] > tau) ? E7[2] * kap1 : E7[3] * kap2; p = (u1 & 128u) ? p : 0.f; dloc += p; af1[7] = (f16)p;
    }

    // advance prefetch: bitmap 2-deep, EF 1-deep
    int nx = (it + 2 < niter) ? (it + 2) : (niter - 1);
    WD = WDn;
    WDn = wbase[(size_t)nx * 32];
    int adv = (it < niter - 1) ? 1 : 0;
    ep += adv * 16;
    E0 = ep[0]; E1 = ep[1]; E2 = ep[2]; E3 = ep[3];
    E4 = ep[8]; E5 = ep[9]; E6 = ep[10]; E7 = ep[11];

    __builtin_amdgcn_s_setprio(1);
    acc[0] = __builtin_amdgcn_mfma_f32_32x32x16_f16(af0, B00, acc[0], 0, 0, 0);
    acc[1] = __builtin_amdgcn_mfma_f32_32x32x16_f16(af0, B01, acc[1], 0, 0, 0);
    acc[2] = __builtin_amdgcn_mfma_f32_32x32x16_f16(af0, B02, acc[2], 0, 0, 0);
    acc[3] = __builtin_amdgcn_mfma_f32_32x32x16_f16(af0, B03, acc[3], 0, 0, 0);
    acc[0] = __builtin_amdgcn_mfma_f32_32x32x16_f16(af1, B10, acc[0], 0, 0, 0);
    acc[1] = __builtin_amdgcn_mfma_f32_32x32x16_f16(af1, B11, acc[1], 0, 0, 0);
    acc[2] = __builtin_amdgcn_mfma_f32_32x32x16_f16(af1, B12, acc[2], 0, 0, 0);
    acc[3] = __builtin_amdgcn_mfma_f32_32x32x16_f16(af1, B13, acc[3], 0, 0, 0);
    __builtin_amdgcn_s_setprio(0);
  }

  // partial denominator: combine kb halves; lanes 0..31 hold rows 0..31
  dloc += __shfl_xor(dloc, 32, 64);
  if (L < 32) Dws[(size_t)c * NROW + row] = dloc;

  // partial numerator: C/D layout col=L&31, row=(reg&3)+8*(reg>>2)+4*kb
  float* P = Pws + ((size_t)c * NROW + rb) * FDIM + (L & 31);
#pragma unroll
  for (int nt = 0; nt < 4; ++nt) {
#pragma unroll
    for (int reg = 0; reg < 16; ++reg) {
      int rr = (reg & 3) + 8 * (reg >> 2) + 4 * kb;
      P[(size_t)rr * FDIM + nt * 32] = acc[nt][reg];
    }
  }
}

// ---------------- k3: combine S partials, ELU ----------------
__global__ __launch_bounds__(256) void k3_comb(const float* __restrict__ Pws,
                                               const float* __restrict__ Dws,
                                               float* __restrict__ out, int S) {
  int g = (int)blockIdx.x * 256 + (int)threadIdx.x;  // 0..262143
  int r = g >> 5, f4 = g & 31;
  f32x4 s = {0.f, 0.f, 0.f, 0.f};
  float den = 0.f;
  for (int c2 = 0; c2 < S; ++c2) {
    s += *(const f32x4*)(Pws + ((size_t)c2 * NROW + r) * FDIM + f4 * 4);
    den += Dws[(size_t)c2 * NROW + r];
  }
  float inv = 1.0f / den;
  f32x4 o;
#pragma unroll
  for (int e = 0; e < 4; ++e) {
    float x = s[e] * inv;
    o[e] = x > 0.f ? x : expm1f(x);
  }
  *(f32x4*)(out + (size_t)r * FDIM + f4 * 4) = o;
}

extern "C" void kernel_launch(void* const* d_in, const int* in_sizes, int n_in,
                              void* d_out, int out_size, void* d_ws, size_t ws_size,
                              hipStream_t stream) {
  const float* h = (const float*)d_in[0];
  const int* adj = (const int*)d_in[1];
  const float* W = (const float*)d_in[2];
  const float* a = (const float*)d_in[3];
  float* out = (float*)d_out;
  char* ws = (char*)d_ws;
  f16* Bp = (f16*)(ws + WS_BP);
  float2* s12 = (float2*)(ws + WS_S12);
  float4* RC = (float4*)(ws + WS_RC);
  float2* EF = (float2*)(ws + WS_EF);
  float* M2v = (float*)(ws + WS_M2);

  // S chunks of j; prefer 16 (4 waves/SIMD in k2), fall back 8 -> 2
  const size_t partial_bytes = (size_t)NROW * FDIM * 4;  // 4 MiB per chunk
  const size_t bm_bytes = (size_t)8 * 1024 * 1024;       // bitmap 8 MiB
  int S = 2;
  if (ws_size >= WS_PWS + 16 * partial_bytes + 16 * (size_t)NROW * 4 + bm_bytes) S = 16;
  else if (ws_size >= WS_PWS + 8 * partial_bytes + 8 * (size_t)NROW * 4 + bm_bytes) S = 8;
  float* Pws = (float*)(ws + WS_PWS);
  float* Dws = (float*)(ws + WS_PWS + (size_t)S * partial_bytes);
  unsigned* BM = (unsigned*)(ws + WS_PWS + (size_t)S * partial_bytes + (size_t)S * NROW * 4);
  int jspan = NROW / S;

  kA_wh_pack<<<dim3(2304), dim3(256), 0, stream>>>(h, W, a, adj, Bp, BM, s12, M2v);
  k1c_prep<<<dim3(32), dim3(256), 0, stream>>>(s12, M2v, RC, EF);
  k2_main<<<dim3(64 * S), dim3(256), 0, stream>>>(BM, Bp, RC, (const float*)EF, Pws, Dws, jspan);
  k3_comb<<<dim3(1024), dim3(256), 0, stream>>>(Pws, Dws, out, S);
}